// Round 2
// baseline (2050.212 us; speedup 1.0000x reference)
//
#include <hip/hip_runtime.h>
#include <stdint.h>

#define B_   64
#define S_   197
#define D_   768
#define H_   12
#define F_   3072
#define BS_  (B_ * S_)   // 12608

typedef __attribute__((ext_vector_type(8))) short short8;
typedef __attribute__((ext_vector_type(4))) float f32x4;

__device__ __forceinline__ float bf2f(unsigned short h) {
    union { unsigned int u; float f; } v; v.u = ((unsigned int)h) << 16; return v.f;
}
__device__ __forceinline__ unsigned short f2bf(float f) {
    union { float f; unsigned int u; } v; v.f = f;
    unsigned int r = v.u + 0x7FFFu + ((v.u >> 16) & 1u);
    return (unsigned short)(r >> 16);
}

__device__ __forceinline__ void g2l16(const void* g, void* l) {
    __builtin_amdgcn_global_load_lds(
        (const __attribute__((address_space(1))) unsigned int*)g,
        (__attribute__((address_space(3))) unsigned int*)l, 16, 0, 0);
}

// ---------------- weight transpose + bf16 cast: W[K][N] f32 -> Wt[N][K] bf16 ----------------
__global__ __launch_bounds__(256)
void transpose_w(const float* __restrict__ W, unsigned short* __restrict__ Wt, int K, int N) {
    __shared__ float t[32][33];
    int n0 = blockIdx.x * 32, k0 = blockIdx.y * 32;
    int tx = threadIdx.x, ty = threadIdx.y;
#pragma unroll
    for (int i = ty; i < 32; i += 8) t[i][tx] = W[(size_t)(k0 + i) * N + n0 + tx];
    __syncthreads();
#pragma unroll
    for (int i = ty; i < 32; i += 8) Wt[(size_t)(n0 + i) * K + k0 + tx] = f2bf(t[tx][i]);
}

__global__ void biascat_kernel(const float* bq, const float* bk, const float* bv, float* o) {
    int i = blockIdx.x * 256 + threadIdx.x;
    if (i < 2304) o[i] = i < 768 ? bq[i] : (i < 1536 ? bk[i - 768] : bv[i - 1536]);
}

// ---------------- LayerNorm: f32 in -> bf16 out (768 = 3*256) ----------------
__global__ __launch_bounds__(256)
void ln_kernel(const float* __restrict__ x, const float* __restrict__ w,
               const float* __restrict__ b, unsigned short* __restrict__ out) {
    int row = blockIdx.x; size_t base = (size_t)row * 768;
    int tid = threadIdx.x;
    float v0 = x[base + tid], v1 = x[base + tid + 256], v2 = x[base + tid + 512];
    float s1 = v0 + v1 + v2;
    float s2 = v0 * v0 + v1 * v1 + v2 * v2;
#pragma unroll
    for (int off = 32; off > 0; off >>= 1) { s1 += __shfl_xor(s1, off); s2 += __shfl_xor(s2, off); }
    __shared__ float sa[4], sb[4];
    int w4 = tid >> 6;
    if ((tid & 63) == 0) { sa[w4] = s1; sb[w4] = s2; }
    __syncthreads();
    s1 = sa[0] + sa[1] + sa[2] + sa[3];
    s2 = sb[0] + sb[1] + sb[2] + sb[3];
    float mean = s1 * (1.f / 768.f);
    float var  = s2 * (1.f / 768.f) - mean * mean;
    float rstd = rsqrtf(var + 1e-6f);
    out[base + tid]       = f2bf((v0 - mean) * rstd * w[tid]       + b[tid]);
    out[base + tid + 256] = f2bf((v1 - mean) * rstd * w[tid + 256] + b[tid + 256]);
    out[base + tid + 512] = f2bf((v2 - mean) * rstd * w[tid + 512] + b[tid + 512]);
}

// ---------------- GEMM: C[M][N] = A[M][K](bf16) * Bt[N][K](bf16)^T + epilogue ----------------
// MODE 0: bf16 out = acc + bias      MODE 1: f32 out = acc + bias + resid      MODE 2: bf16 out = gelu(acc + bias)
template<int MODE>
__global__ __launch_bounds__(256)
void gemm_bf16(const unsigned short* __restrict__ A, const unsigned short* __restrict__ Bt,
               const float* __restrict__ bias, const float* __restrict__ resid,
               void* __restrict__ out, int M, int N, int K) {
    __shared__ unsigned short As[128 * 32];
    __shared__ unsigned short Bs[128 * 32];
    const int tid = threadIdx.x;
    const int l = tid & 63, w = tid >> 6;
    const int lr = l & 15, lg = l >> 4;
    const int wr = w >> 1, wc = w & 1;
    const int bm0 = blockIdx.y * 128, bn0 = blockIdx.x * 128;

    f32x4 acc[4][4];
#pragma unroll
    for (int i = 0; i < 4; ++i)
#pragma unroll
        for (int j = 0; j < 4; ++j) acc[i][j] = (f32x4){0.f, 0.f, 0.f, 0.f};

    for (int k0 = 0; k0 < K; k0 += 32) {
        __syncthreads();
#pragma unroll
        for (int p = 0; p < 2; ++p) {
            int r0 = p * 64 + w * 16;
            int ra = bm0 + r0 + (l >> 2); ra = ra < M ? ra : M - 1;
            g2l16(A + (size_t)ra * K + k0 + (l & 3) * 8, &As[r0 * 32]);
            int rb = bn0 + r0 + (l >> 2);
            g2l16(Bt + (size_t)rb * K + k0 + (l & 3) * 8, &Bs[r0 * 32]);
        }
        __syncthreads();
        short8 af[4], bfr[4];
#pragma unroll
        for (int i = 0; i < 4; ++i) af[i]  = *(const short8*)&As[(wr * 64 + i * 16 + lr) * 32 + lg * 8];
#pragma unroll
        for (int j = 0; j < 4; ++j) bfr[j] = *(const short8*)&Bs[(wc * 64 + j * 16 + lr) * 32 + lg * 8];
#pragma unroll
        for (int i = 0; i < 4; ++i)
#pragma unroll
            for (int j = 0; j < 4; ++j)
                acc[i][j] = __builtin_amdgcn_mfma_f32_16x16x32_bf16(af[i], bfr[j], acc[i][j], 0, 0, 0);
    }
#pragma unroll
    for (int i = 0; i < 4; ++i)
#pragma unroll
        for (int j = 0; j < 4; ++j)
#pragma unroll
            for (int r = 0; r < 4; ++r) {
                int gm = bm0 + wr * 64 + i * 16 + lg * 4 + r;
                int gn = bn0 + wc * 64 + j * 16 + lr;
                if (gm < M) {
                    float c = acc[i][j][r] + bias[gn];
                    if (MODE == 0) {
                        ((unsigned short*)out)[(size_t)gm * N + gn] = f2bf(c);
                    } else if (MODE == 1) {
                        ((float*)out)[(size_t)gm * N + gn] = c + resid[(size_t)gm * N + gn];
                    } else {
                        float g = 0.5f * c * (1.f + erff(c * 0.70710678118f));
                        ((unsigned short*)out)[(size_t)gm * N + gn] = f2bf(g);
                    }
                }
            }
}

// ---------------- repack K into Kt[b][h][d][j] f32 for the attention kernel ----------------
__global__ __launch_bounds__(256)
void repack_kt(const unsigned short* __restrict__ qkv, float* __restrict__ kt) {
    int bh = blockIdx.x; int b = bh / 12, h = bh - b * 12;
    __shared__ float t[197][68];
    int tid = threadIdx.x;
    const unsigned short* kg = qkv + (size_t)b * 197 * 2304 + 768 + h * 64;
    for (int i = tid; i < 197 * 64; i += 256) { int j = i >> 6, d = i & 63; t[j][d] = bf2f(kg[(size_t)j * 2304 + d]); }
    __syncthreads();
    float* o = kt + (size_t)bh * 64 * 197;
    for (int i = tid; i < 64 * 197; i += 256) { int d = i / 197, j = i - d * 197; o[i] = t[j][d]; }
}

// ---------------- attention: one block per (b,h), 4 waves, fp32 ----------------
__global__ __launch_bounds__(256)
void attn_kernel(const unsigned short* __restrict__ qkv, const float* __restrict__ kt,
                 const int* __restrict__ mask, unsigned short* __restrict__ ctx) {
    int bh = blockIdx.x; int b = bh / 12, h = bh - b * 12;
    __shared__ float kts[64][200];
    __shared__ float ps[4][200];
    __shared__ float qs[4][64];
    int tid = threadIdx.x, l = tid & 63, w = tid >> 6;
    const float* ktg = kt + (size_t)bh * 64 * 197;
    for (int d = w; d < 64; d += 4)
        for (int c = l; c < 197; c += 64) kts[d][c] = ktg[d * 197 + c];
    __syncthreads();
    const unsigned short* qg = qkv + (size_t)b * 197 * 2304 + h * 64;
    const unsigned short* vg = qkv + (size_t)b * 197 * 2304 + 1536 + h * 64;
    for (int row = w; row < 197; row += 4) {
        float qv = bf2f(qg[(size_t)row * 2304 + l]) * 0.125f;  // fold 1/sqrt(64)
        qs[w][l] = qv;
        asm volatile("s_waitcnt lgkmcnt(0)" ::: "memory");
        __builtin_amdgcn_sched_barrier(0);
        float s[4] = {-3.0e38f, -3.0e38f, -3.0e38f, -3.0e38f};
        if (l < 50) {
            s[0] = s[1] = s[2] = s[3] = 0.f;
            const float* kp = &kts[0][4 * l];
#pragma unroll 8
            for (int d = 0; d < 64; ++d) {
                float qd = qs[w][d];
                float4 kv = *(const float4*)(kp + d * 200);
                s[0] += kv.x * qd; s[1] += kv.y * qd; s[2] += kv.z * qd; s[3] += kv.w * qd;
            }
            int j0 = 4 * l;
#pragma unroll
            for (int c = 0; c < 4; ++c) {
                int key = j0 + c;
                if (key < 197) s[c] -= 10000.f * (1.f - (float)mask[b * 197 + key]);
                else           s[c] = -3.0e38f;
            }
        }
        float mx = fmaxf(fmaxf(s[0], s[1]), fmaxf(s[2], s[3]));
#pragma unroll
        for (int off = 32; off > 0; off >>= 1) mx = fmaxf(mx, __shfl_xor(mx, off));
        float e0 = __expf(s[0] - mx), e1 = __expf(s[1] - mx);
        float e2 = __expf(s[2] - mx), e3 = __expf(s[3] - mx);
        float sum = e0 + e1 + e2 + e3;
#pragma unroll
        for (int off = 32; off > 0; off >>= 1) sum += __shfl_xor(sum, off);
        if (l < 50) { float4 pv = {e0, e1, e2, e3}; *(float4*)&ps[w][4 * l] = pv; }
        asm volatile("s_waitcnt lgkmcnt(0)" ::: "memory");
        __builtin_amdgcn_sched_barrier(0);
        float o = 0.f;
        const unsigned short* vrow = vg + l;
#pragma unroll 4
        for (int j = 0; j < 197; ++j) o += ps[w][j] * bf2f(vrow[(size_t)j * 2304]);
        ctx[((size_t)b * 197 + row) * 768 + h * 64 + l] = f2bf(o / sum);
    }
}

extern "C" void kernel_launch(void* const* d_in, const int* in_sizes, int n_in,
                              void* d_out, int out_size, void* d_ws, size_t ws_size,
                              hipStream_t stream) {
    const float* x    = (const float*)d_in[0];
    const float* Wq   = (const float*)d_in[1];
    const float* bq   = (const float*)d_in[2];
    const float* Wk   = (const float*)d_in[3];
    const float* bk   = (const float*)d_in[4];
    const float* Wv   = (const float*)d_in[5];
    const float* bv   = (const float*)d_in[6];
    const float* Wo   = (const float*)d_in[7];
    const float* bo   = (const float*)d_in[8];
    const float* ln1w = (const float*)d_in[9];
    const float* ln1b = (const float*)d_in[10];
    const float* W1   = (const float*)d_in[11];
    const float* b1   = (const float*)d_in[12];
    const float* W2   = (const float*)d_in[13];
    const float* b2   = (const float*)d_in[14];
    const float* ln2w = (const float*)d_in[15];
    const float* ln2b = (const float*)d_in[16];
    const int*   mask = (const int*)d_in[17];

    size_t off = 0;
    auto nxt = [&](size_t bytes) -> void* {
        void* r = (char*)d_ws + off; off += (bytes + 255) & ~(size_t)255; return r;
    };
    unsigned short* hbuf  = (unsigned short*)nxt((size_t)BS_ * 768 * 2);
    unsigned short* qkvg  = (unsigned short*)nxt((size_t)BS_ * 3072 * 2);  // QKV (2304 cols) then reused as FFN1 out (3072)
    unsigned short* wqkvT = (unsigned short*)nxt((size_t)2304 * 768 * 2);
    unsigned short* woT   = (unsigned short*)nxt((size_t)768 * 768 * 2);
    unsigned short* w1T   = (unsigned short*)nxt((size_t)3072 * 768 * 2);
    unsigned short* w2T   = (unsigned short*)nxt((size_t)768 * 3072 * 2);
    float*          bcat  = (float*)nxt(2304 * 4);
    float*          ktbuf = (float*)nxt((size_t)768 * 64 * 197 * 4);
    unsigned short* ctx   = (unsigned short*)nxt((size_t)BS_ * 768 * 2);
    (void)ws_size; (void)in_sizes; (void)n_in; (void)out_size;

    dim3 t32(32, 8, 1);
    transpose_w<<<dim3(24, 24), t32, 0, stream>>>(Wq, wqkvT,                 768, 768);
    transpose_w<<<dim3(24, 24), t32, 0, stream>>>(Wk, wqkvT + 768 * 768,     768, 768);
    transpose_w<<<dim3(24, 24), t32, 0, stream>>>(Wv, wqkvT + 2 * 768 * 768, 768, 768);
    transpose_w<<<dim3(24, 24), t32, 0, stream>>>(Wo, woT,                   768, 768);
    transpose_w<<<dim3(96, 24), t32, 0, stream>>>(W1, w1T,                   768, 3072);
    transpose_w<<<dim3(24, 96), t32, 0, stream>>>(W2, w2T,                   3072, 768);
    biascat_kernel<<<9, 256, 0, stream>>>(bq, bk, bv, bcat);

    ln_kernel<<<BS_, 256, 0, stream>>>(x, ln1w, ln1b, hbuf);
    gemm_bf16<0><<<dim3(18, 99), 256, 0, stream>>>(hbuf, wqkvT, bcat, nullptr, qkvg, BS_, 2304, 768);
    repack_kt<<<768, 256, 0, stream>>>(qkvg, ktbuf);
    attn_kernel<<<768, 256, 0, stream>>>(qkvg, ktbuf, mask, ctx);
    gemm_bf16<1><<<dim3(6, 99), 256, 0, stream>>>(ctx, woT, bo, x, d_out, BS_, 768, 768);
    ln_kernel<<<BS_, 256, 0, stream>>>((const float*)d_out, ln2w, ln2b, hbuf);
    gemm_bf16<2><<<dim3(24, 99), 256, 0, stream>>>(hbuf, w1T, b1, nullptr, qkvg, BS_, 3072, 768);
    gemm_bf16<1><<<dim3(6, 99), 256, 0, stream>>>(qkvg, w2T, b2, (const float*)d_out, d_out, BS_, 768, 3072);
}

// Round 3
// 506.570 us; speedup vs baseline: 4.0472x; 4.0472x over previous
//
#include <hip/hip_runtime.h>
#include <stdint.h>

#define B_   64
#define S_   197
#define D_   768
#define H_   12
#define F_   3072
#define BS_  (B_ * S_)   // 12608

typedef __attribute__((ext_vector_type(8))) short short8;
typedef __attribute__((ext_vector_type(4))) float f32x4;

__device__ __forceinline__ float bf2f(unsigned short h) {
    union { unsigned int u; float f; } v; v.u = ((unsigned int)h) << 16; return v.f;
}
__device__ __forceinline__ unsigned short f2bf(float f) {
    union { float f; unsigned int u; } v; v.f = f;
    unsigned int r = v.u + 0x7FFFu + ((v.u >> 16) & 1u);
    return (unsigned short)(r >> 16);
}

__device__ __forceinline__ void g2l16(const void* g, void* l) {
    __builtin_amdgcn_global_load_lds(
        (const __attribute__((address_space(1))) unsigned int*)g,
        (__attribute__((address_space(3))) unsigned int*)l, 16, 0, 0);
}

// ---------------- weight transpose + bf16 cast: W[K][N] f32 -> Wt[N][K] bf16 ----------------
__global__ __launch_bounds__(256)
void transpose_w(const float* __restrict__ W, unsigned short* __restrict__ Wt, int K, int N) {
    __shared__ float t[32][33];
    int n0 = blockIdx.x * 32, k0 = blockIdx.y * 32;
    int tx = threadIdx.x, ty = threadIdx.y;
#pragma unroll
    for (int i = ty; i < 32; i += 8) t[i][tx] = W[(size_t)(k0 + i) * N + n0 + tx];
    __syncthreads();
#pragma unroll
    for (int i = ty; i < 32; i += 8) Wt[(size_t)(n0 + i) * K + k0 + tx] = f2bf(t[tx][i]);
}

__global__ void biascat_kernel(const float* bq, const float* bk, const float* bv, float* o) {
    int i = blockIdx.x * 256 + threadIdx.x;
    if (i < 2304) o[i] = i < 768 ? bq[i] : (i < 1536 ? bk[i - 768] : bv[i - 1536]);
}

// ---------------- LayerNorm: f32 in -> bf16 out (768 = 3*256) ----------------
__global__ __launch_bounds__(256)
void ln_kernel(const float* __restrict__ x, const float* __restrict__ w,
               const float* __restrict__ b, unsigned short* __restrict__ out) {
    int row = blockIdx.x; size_t base = (size_t)row * 768;
    int tid = threadIdx.x;
    float v0 = x[base + tid], v1 = x[base + tid + 256], v2 = x[base + tid + 512];
    float s1 = v0 + v1 + v2;
    float s2 = v0 * v0 + v1 * v1 + v2 * v2;
#pragma unroll
    for (int off = 32; off > 0; off >>= 1) { s1 += __shfl_xor(s1, off); s2 += __shfl_xor(s2, off); }
    __shared__ float sa[4], sb[4];
    int w4 = tid >> 6;
    if ((tid & 63) == 0) { sa[w4] = s1; sb[w4] = s2; }
    __syncthreads();
    s1 = sa[0] + sa[1] + sa[2] + sa[3];
    s2 = sb[0] + sb[1] + sb[2] + sb[3];
    float mean = s1 * (1.f / 768.f);
    float var  = s2 * (1.f / 768.f) - mean * mean;
    float rstd = rsqrtf(var + 1e-6f);
    out[base + tid]       = f2bf((v0 - mean) * rstd * w[tid]       + b[tid]);
    out[base + tid + 256] = f2bf((v1 - mean) * rstd * w[tid + 256] + b[tid + 256]);
    out[base + tid + 512] = f2bf((v2 - mean) * rstd * w[tid + 512] + b[tid + 512]);
}

// ---------------- GEMM: C[M][N] = A[M][K](bf16) * Bt[N][K](bf16)^T + epilogue ----------------
// MODE 0: bf16 out = acc + bias (cols<768 pre-scaled by 0.125 for attention Q)
// MODE 1: f32 out = acc + bias + resid      MODE 2: bf16 out = gelu(acc + bias)
template<int MODE>
__global__ __launch_bounds__(256)
void gemm_bf16(const unsigned short* __restrict__ A, const unsigned short* __restrict__ Bt,
               const float* __restrict__ bias, const float* __restrict__ resid,
               void* __restrict__ out, int M, int N, int K) {
    __shared__ unsigned short As[128 * 32];
    __shared__ unsigned short Bs[128 * 32];
    const int tid = threadIdx.x;
    const int l = tid & 63, w = tid >> 6;
    const int lr = l & 15, lg = l >> 4;
    const int wr = w >> 1, wc = w & 1;
    const int bm0 = blockIdx.y * 128, bn0 = blockIdx.x * 128;

    f32x4 acc[4][4];
#pragma unroll
    for (int i = 0; i < 4; ++i)
#pragma unroll
        for (int j = 0; j < 4; ++j) acc[i][j] = (f32x4){0.f, 0.f, 0.f, 0.f};

    for (int k0 = 0; k0 < K; k0 += 32) {
        __syncthreads();
#pragma unroll
        for (int p = 0; p < 2; ++p) {
            int r0 = p * 64 + w * 16;
            int ra = bm0 + r0 + (l >> 2); ra = ra < M ? ra : M - 1;
            g2l16(A + (size_t)ra * K + k0 + (l & 3) * 8, &As[r0 * 32]);
            int rb = bn0 + r0 + (l >> 2);
            g2l16(Bt + (size_t)rb * K + k0 + (l & 3) * 8, &Bs[r0 * 32]);
        }
        __syncthreads();
        short8 af[4], bfr[4];
#pragma unroll
        for (int i = 0; i < 4; ++i) af[i]  = *(const short8*)&As[(wr * 64 + i * 16 + lr) * 32 + lg * 8];
#pragma unroll
        for (int j = 0; j < 4; ++j) bfr[j] = *(const short8*)&Bs[(wc * 64 + j * 16 + lr) * 32 + lg * 8];
#pragma unroll
        for (int i = 0; i < 4; ++i)
#pragma unroll
            for (int j = 0; j < 4; ++j)
                acc[i][j] = __builtin_amdgcn_mfma_f32_16x16x32_bf16(af[i], bfr[j], acc[i][j], 0, 0, 0);
    }
#pragma unroll
    for (int i = 0; i < 4; ++i)
#pragma unroll
        for (int j = 0; j < 4; ++j)
#pragma unroll
            for (int r = 0; r < 4; ++r) {
                int gm = bm0 + wr * 64 + i * 16 + lg * 4 + r;
                int gn = bn0 + wc * 64 + j * 16 + lr;
                if (gm < M) {
                    float c = acc[i][j][r] + bias[gn];
                    if (MODE == 0) {
                        if (gn < 768) c *= 0.125f;  // fold 1/sqrt(Dh) into Q
                        ((unsigned short*)out)[(size_t)gm * N + gn] = f2bf(c);
                    } else if (MODE == 1) {
                        ((float*)out)[(size_t)gm * N + gn] = c + resid[(size_t)gm * N + gn];
                    } else {
                        float g = 0.5f * c * (1.f + erff(c * 0.70710678118f));
                        ((unsigned short*)out)[(size_t)gm * N + gn] = f2bf(g);
                    }
                }
            }
}

// ---------------- MFMA attention: one block per (b,h), 4 waves ----------------
// K_lds: [208 rows][64 d] bf16, 16B-block XOR swizzle (blk ^= row&7) via pre-swizzled
//        global_load_lds source (linear LDS dest).
// Vt:    [64 d][256 keys] bf16 (keys >=197 zeroed), blk ^= d&7 swizzle.
// Scores for a 16-row q-tile live in registers (13 x f32x4, C/D layout:
//        q = lg*4+r, key = kt*16+lr). Softmax reduces across lr via shfl_xor.
// PV via per-wave 16x32 P-slice LDS buffer (layout conversion C/D -> A/B frag).
__global__ __launch_bounds__(256)
void attn_mfma(const unsigned short* __restrict__ qkv, const int* __restrict__ mask,
               unsigned short* __restrict__ ctx) {
    __shared__ unsigned short Ks[208 * 64];
    __shared__ unsigned short Vt[64 * 256];
    __shared__ unsigned short Psl[4][16 * 40];   // 40-short row stride: 16B-aligned, bank-spread
    __shared__ float maskadj[224];
    const int bh = blockIdx.x, b = bh / 12, h = bh - b * 12;
    const int tid = threadIdx.x, l = tid & 63, w = tid >> 6;
    const int lr = l & 15, lg = l >> 4;
    const unsigned short* Qg = qkv + (size_t)b * 197 * 2304 + h * 64;
    const unsigned short* Kg = Qg + 768;
    const unsigned short* Vg = Qg + 1536;

    if (tid < 224)
        maskadj[tid] = tid < 197 ? -10000.f * (1.f - (float)mask[b * 197 + tid]) : -1e30f;

    // ---- stage K: 26 groups x 8 rows, swizzled source, linear LDS dest ----
    for (int c = w; c < 26; c += 4) {
        int row = c * 8 + (l >> 3);
        int rc = row < 197 ? row : 196;          // pad rows: finite clone, masked later
        int blk = (l & 7) ^ (row & 7);
        g2l16(Kg + (size_t)rc * 2304 + blk * 8, &Ks[c * 8 * 64]);
    }
    // ---- stage V transposed (+zero pad keys 197..255 region used: ..223) ----
    {
        int jj = tid >> 3, db = tid & 7;
#pragma unroll
        for (int it = 0; it < 7; ++it) {
            int j = it * 32 + jj;                // covers 0..223
            short8 v = (short8){0, 0, 0, 0, 0, 0, 0, 0};
            if (j < 197) v = *(const short8*)(Vg + (size_t)j * 2304 + db * 8);
#pragma unroll
            for (int e = 0; e < 8; ++e) {
                int d = db * 8 + e;
                Vt[d * 256 + (((j >> 3) ^ (d & 7)) * 8) + (j & 7)] = (unsigned short)v[e];
            }
        }
    }
    __syncthreads();

    // ---- per-wave q-tiles (13 tiles of 16 rows; waves get 4/3/3/3) ----
    for (int t = w; t < 13; t += 4) {
        const int q0 = t * 16;
        int qr = q0 + lr; qr = qr < 197 ? qr : 196;
        const short8 qf0 = *(const short8*)(Qg + (size_t)qr * 2304 + lg * 8);
        const short8 qf1 = *(const short8*)(Qg + (size_t)qr * 2304 + 32 + lg * 8);

        f32x4 sc[13];
#pragma unroll
        for (int kt = 0; kt < 13; ++kt) {
            const int krow = kt * 16 + lr;
            const short8 kf0 = *(const short8*)&Ks[krow * 64 + ((lg ^ (lr & 7)) * 8)];
            const short8 kf1 = *(const short8*)&Ks[krow * 64 + (((4 + lg) ^ (lr & 7)) * 8)];
            f32x4 a = (f32x4){0.f, 0.f, 0.f, 0.f};
            a = __builtin_amdgcn_mfma_f32_16x16x32_bf16(qf0, kf0, a, 0, 0, 0);
            a = __builtin_amdgcn_mfma_f32_16x16x32_bf16(qf1, kf1, a, 0, 0, 0);
            sc[kt] = a;
        }
        // mask + row max (Q already scaled by 0.125 in QKV epilogue)
        float mx[4] = {-1e30f, -1e30f, -1e30f, -1e30f};
#pragma unroll
        for (int kt = 0; kt < 13; ++kt) {
            float ma = maskadj[kt * 16 + lr];
#pragma unroll
            for (int r = 0; r < 4; ++r) {
                sc[kt][r] += ma;
                mx[r] = fmaxf(mx[r], sc[kt][r]);
            }
        }
#pragma unroll
        for (int r = 0; r < 4; ++r) {
            mx[r] = fmaxf(mx[r], __shfl_xor(mx[r], 1));
            mx[r] = fmaxf(mx[r], __shfl_xor(mx[r], 2));
            mx[r] = fmaxf(mx[r], __shfl_xor(mx[r], 4));
            mx[r] = fmaxf(mx[r], __shfl_xor(mx[r], 8));
        }
        float sm[4] = {0.f, 0.f, 0.f, 0.f};
#pragma unroll
        for (int kt = 0; kt < 13; ++kt)
#pragma unroll
            for (int r = 0; r < 4; ++r) {
                float p = __expf(sc[kt][r] - mx[r]);
                sc[kt][r] = p;
                sm[r] += p;
            }
#pragma unroll
        for (int r = 0; r < 4; ++r) {
            sm[r] += __shfl_xor(sm[r], 1);
            sm[r] += __shfl_xor(sm[r], 2);
            sm[r] += __shfl_xor(sm[r], 4);
            sm[r] += __shfl_xor(sm[r], 8);
            sm[r] = 1.f / sm[r];                 // fold 1/sum into P
        }
        // ---- PV: per-32-key slices through the per-wave P buffer ----
        f32x4 ao[4];
#pragma unroll
        for (int dt = 0; dt < 4; ++dt) ao[dt] = (f32x4){0.f, 0.f, 0.f, 0.f};
        unsigned short* Pw = &Psl[w][0];
#pragma unroll
        for (int ks = 0; ks < 7; ++ks) {
#pragma unroll
            for (int tl = 0; tl < 2; ++tl) {
                const int kt = ks * 2 + tl;
#pragma unroll
                for (int r = 0; r < 4; ++r) {
                    unsigned short pv = 0;
                    if (kt < 13) pv = f2bf(sc[kt][r] * sm[r]);
                    Pw[(lg * 4 + r) * 40 + tl * 16 + lr] = pv;
                }
            }
            const short8 pf = *(const short8*)&Pw[lr * 40 + lg * 8];
#pragma unroll
            for (int dt = 0; dt < 4; ++dt) {
                const int drow = dt * 16 + lr;
                const short8 vf = *(const short8*)&Vt[drow * 256 + (((4 * ks + lg) ^ (lr & 7)) * 8)];
                ao[dt] = __builtin_amdgcn_mfma_f32_16x16x32_bf16(vf, pf, ao[dt], 0, 0, 0);
            }
        }
        // ---- store: lane holds O^T[d = dt*16+lg*4+r][q = q0+lr] ----
        const int q = q0 + lr;
        if (q < 197) {
            unsigned short* crow = ctx + ((size_t)b * 197 + q) * 768 + h * 64;
#pragma unroll
            for (int dt = 0; dt < 4; ++dt) {
                union { unsigned short u[4]; uint2 v; } pk;
#pragma unroll
                for (int r = 0; r < 4; ++r) pk.u[r] = f2bf(ao[dt][r]);
                *(uint2*)(crow + dt * 16 + lg * 4) = pk.v;
            }
        }
    }
}

extern "C" void kernel_launch(void* const* d_in, const int* in_sizes, int n_in,
                              void* d_out, int out_size, void* d_ws, size_t ws_size,
                              hipStream_t stream) {
    const float* x    = (const float*)d_in[0];
    const float* Wq   = (const float*)d_in[1];
    const float* bq   = (const float*)d_in[2];
    const float* Wk   = (const float*)d_in[3];
    const float* bk   = (const float*)d_in[4];
    const float* Wv   = (const float*)d_in[5];
    const float* bv   = (const float*)d_in[6];
    const float* Wo   = (const float*)d_in[7];
    const float* bo   = (const float*)d_in[8];
    const float* ln1w = (const float*)d_in[9];
    const float* ln1b = (const float*)d_in[10];
    const float* W1   = (const float*)d_in[11];
    const float* b1   = (const float*)d_in[12];
    const float* W2   = (const float*)d_in[13];
    const float* b2   = (const float*)d_in[14];
    const float* ln2w = (const float*)d_in[15];
    const float* ln2b = (const float*)d_in[16];
    const int*   mask = (const int*)d_in[17];

    size_t off = 0;
    auto nxt = [&](size_t bytes) -> void* {
        void* r = (char*)d_ws + off; off += (bytes + 255) & ~(size_t)255; return r;
    };
    unsigned short* hbuf  = (unsigned short*)nxt((size_t)BS_ * 768 * 2);
    unsigned short* qkvg  = (unsigned short*)nxt((size_t)BS_ * 3072 * 2);  // QKV (2304 cols), reused as FFN1 out (3072)
    unsigned short* wqkvT = (unsigned short*)nxt((size_t)2304 * 768 * 2);
    unsigned short* woT   = (unsigned short*)nxt((size_t)768 * 768 * 2);
    unsigned short* w1T   = (unsigned short*)nxt((size_t)3072 * 768 * 2);
    unsigned short* w2T   = (unsigned short*)nxt((size_t)768 * 3072 * 2);
    float*          bcat  = (float*)nxt(2304 * 4);
    unsigned short* ctx   = (unsigned short*)nxt((size_t)BS_ * 768 * 2);
    (void)ws_size; (void)in_sizes; (void)n_in; (void)out_size;

    dim3 t32(32, 8, 1);
    transpose_w<<<dim3(24, 24), t32, 0, stream>>>(Wq, wqkvT,                 768, 768);
    transpose_w<<<dim3(24, 24), t32, 0, stream>>>(Wk, wqkvT + 768 * 768,     768, 768);
    transpose_w<<<dim3(24, 24), t32, 0, stream>>>(Wv, wqkvT + 2 * 768 * 768, 768, 768);
    transpose_w<<<dim3(24, 24), t32, 0, stream>>>(Wo, woT,                   768, 768);
    transpose_w<<<dim3(96, 24), t32, 0, stream>>>(W1, w1T,                   768, 3072);
    transpose_w<<<dim3(24, 96), t32, 0, stream>>>(W2, w2T,                   3072, 768);
    biascat_kernel<<<9, 256, 0, stream>>>(bq, bk, bv, bcat);

    ln_kernel<<<BS_, 256, 0, stream>>>(x, ln1w, ln1b, hbuf);
    gemm_bf16<0><<<dim3(18, 99), 256, 0, stream>>>(hbuf, wqkvT, bcat, nullptr, qkvg, BS_, 2304, 768);
    attn_mfma<<<768, 256, 0, stream>>>(qkvg, mask, ctx);
    gemm_bf16<1><<<dim3(6, 99), 256, 0, stream>>>(ctx, woT, bo, x, d_out, BS_, 768, 768);
    ln_kernel<<<BS_, 256, 0, stream>>>((const float*)d_out, ln2w, ln2b, hbuf);
    gemm_bf16<2><<<dim3(24, 99), 256, 0, stream>>>(hbuf, w1T, b1, nullptr, qkvg, BS_, 3072, 768);
    gemm_bf16<1><<<dim3(6, 99), 256, 0, stream>>>(qkvg, w2T, b2, (const float*)d_out, d_out, BS_, 768, 3072);
}

// Round 4
// 482.780 us; speedup vs baseline: 4.2467x; 1.0493x over previous
//
#include <hip/hip_runtime.h>
#include <stdint.h>

#define B_   64
#define S_   197
#define D_   768
#define H_   12
#define F_   3072
#define BS_  (B_ * S_)   // 12608

typedef __attribute__((ext_vector_type(8))) short short8;
typedef __attribute__((ext_vector_type(4))) float f32x4;

__device__ __forceinline__ float bf2f(unsigned short h) {
    union { unsigned int u; float f; } v; v.u = ((unsigned int)h) << 16; return v.f;
}
__device__ __forceinline__ unsigned short f2bf(float f) {
    union { float f; unsigned int u; } v; v.f = f;
    unsigned int r = v.u + 0x7FFFu + ((v.u >> 16) & 1u);
    return (unsigned short)(r >> 16);
}

__device__ __forceinline__ void g2l16(const void* g, void* l) {
    __builtin_amdgcn_global_load_lds(
        (const __attribute__((address_space(1))) unsigned int*)g,
        (__attribute__((address_space(3))) unsigned int*)l, 16, 0, 0);
}

// ---------------- fused weight transpose + bf16 cast + bias concat ----------------
// 6 matrices W[K][N] f32 -> Wt[N][K] bf16, one 32x32 tile per block; block 6912 = bias concat.
__global__ __launch_bounds__(256)
void transpose_all(const float* __restrict__ Wq, const float* __restrict__ Wk,
                   const float* __restrict__ Wv, const float* __restrict__ Wo,
                   const float* __restrict__ W1, const float* __restrict__ W2,
                   const float* __restrict__ bq, const float* __restrict__ bk,
                   const float* __restrict__ bv,
                   unsigned short* __restrict__ wqkvT, unsigned short* __restrict__ woT,
                   unsigned short* __restrict__ w1T, unsigned short* __restrict__ w2T,
                   float* __restrict__ bcat) {
    int blk = blockIdx.x;
    int tx = threadIdx.x, ty = threadIdx.y;
    if (blk == 6912) {
        for (int i = ty * 32 + tx; i < 2304; i += 256)
            bcat[i] = i < 768 ? bq[i] : (i < 1536 ? bk[i - 768] : bv[i - 1536]);
        return;
    }
    const float* W; unsigned short* Wt; int K, N, rel, nx;
    if (blk < 2304) {
        int m = blk / 576; rel = blk - m * 576; K = 768; N = 768; nx = 24;
        W  = m == 0 ? Wq : m == 1 ? Wk : m == 2 ? Wv : Wo;
        Wt = m < 3 ? wqkvT + (size_t)m * 768 * 768 : woT;
    } else if (blk < 4608) {
        rel = blk - 2304; K = 768; N = 3072; nx = 96; W = W1; Wt = w1T;
    } else {
        rel = blk - 4608; K = 3072; N = 768; nx = 24; W = W2; Wt = w2T;
    }
    int n0 = (rel % nx) * 32, k0 = (rel / nx) * 32;
    __shared__ float t[32][33];
#pragma unroll
    for (int i = ty; i < 32; i += 8) t[i][tx] = W[(size_t)(k0 + i) * N + n0 + tx];
    __syncthreads();
#pragma unroll
    for (int i = ty; i < 32; i += 8) Wt[(size_t)(n0 + i) * K + k0 + tx] = f2bf(t[tx][i]);
}

// ---------------- LayerNorm: f32 in -> bf16 out (768 = 3*256) ----------------
__global__ __launch_bounds__(256)
void ln_kernel(const float* __restrict__ x, const float* __restrict__ w,
               const float* __restrict__ b, unsigned short* __restrict__ out) {
    int row = blockIdx.x; size_t base = (size_t)row * 768;
    int tid = threadIdx.x;
    float v0 = x[base + tid], v1 = x[base + tid + 256], v2 = x[base + tid + 512];
    float s1 = v0 + v1 + v2;
    float s2 = v0 * v0 + v1 * v1 + v2 * v2;
#pragma unroll
    for (int off = 32; off > 0; off >>= 1) { s1 += __shfl_xor(s1, off); s2 += __shfl_xor(s2, off); }
    __shared__ float sa[4], sb[4];
    int w4 = tid >> 6;
    if ((tid & 63) == 0) { sa[w4] = s1; sb[w4] = s2; }
    __syncthreads();
    s1 = sa[0] + sa[1] + sa[2] + sa[3];
    s2 = sb[0] + sb[1] + sb[2] + sb[3];
    float mean = s1 * (1.f / 768.f);
    float var  = s2 * (1.f / 768.f) - mean * mean;
    float rstd = rsqrtf(var + 1e-6f);
    out[base + tid]       = f2bf((v0 - mean) * rstd * w[tid]       + b[tid]);
    out[base + tid + 256] = f2bf((v1 - mean) * rstd * w[tid + 256] + b[tid + 256]);
    out[base + tid + 512] = f2bf((v2 - mean) * rstd * w[tid + 512] + b[tid + 512]);
}

// ---------------- GEMM v2: double-buffered, LDS-swizzled, XCD-chunked ----------------
// C[M][N] = A[M][K](bf16) * Bt[N][K](bf16)^T + epilogue
// MODE 0: bf16 out = acc + bias (cols<768 pre-scaled by 0.125 for attention Q)
// MODE 1: f32 out = acc + bias + resid      MODE 2: bf16 out = gelu(acc + bias)
// LDS swizzle: 16B block phys = log ^ ((row>>1)&3)  (conflict-free ds_read_b128;
// staged via pre-swizzled global source, linear LDS dest -- rule 21).
template<int MODE>
__global__ __launch_bounds__(256)
void gemm_bf16(const unsigned short* __restrict__ A, const unsigned short* __restrict__ Bt,
               const float* __restrict__ bias, const float* __restrict__ resid,
               void* __restrict__ out, int M, int N, int K) {
    __shared__ unsigned short As[2][128 * 32];
    __shared__ unsigned short Bs[2][128 * 32];
    const int tid = threadIdx.x;
    const int l = tid & 63, w = tid >> 6;
    const int lr = l & 15, lg = l >> 4;
    const int wr = w >> 1, wc = w & 1;

    // --- bijective XCD-chunked swizzle (m204), M-fastest within a chunk ---
    const int nMt = gridDim.y;                       // 99
    const int nwg = gridDim.x * gridDim.y;
    const int orig = blockIdx.x + gridDim.x * blockIdx.y;
    const int q8 = nwg >> 3, r8 = nwg & 7;
    const int xcd = orig & 7, idx = orig >> 3;
    const int wgid = (xcd < r8 ? xcd * (q8 + 1) : r8 * (q8 + 1) + (xcd - r8) * q8) + idx;
    const int bm0 = (wgid % nMt) * 128;
    const int bn0 = (wgid / nMt) * 128;

    // stage one 128x32 A-tile + B-tile into buffer `buf` (pre-swizzled source)
    const int srow = l >> 2;                         // lane's LDS row within 16-row group
    const int sblk = (l & 3) ^ ((l >> 3) & 3);       // logical 16B block for this phys slot
    auto stage = [&](int buf, int k0) {
#pragma unroll
        for (int p = 0; p < 2; ++p) {
            int r0 = p * 64 + w * 16;
            int ra = bm0 + r0 + srow; ra = ra < M ? ra : M - 1;
            g2l16(A + (size_t)ra * K + k0 + sblk * 8, &As[buf][r0 * 32]);
            int rb = bn0 + r0 + srow;
            g2l16(Bt + (size_t)rb * K + k0 + sblk * 8, &Bs[buf][r0 * 32]);
        }
    };

    f32x4 acc[4][4];
#pragma unroll
    for (int i = 0; i < 4; ++i)
#pragma unroll
        for (int j = 0; j < 4; ++j) acc[i][j] = (f32x4){0.f, 0.f, 0.f, 0.f};

    stage(0, 0);
    __syncthreads();                                  // drains vmcnt(0) (compiler barrier semantics)
    int cur = 0;
    const int NK = K >> 5;
    const int rblk = lg ^ ((lr >> 1) & 3);            // read-side swizzled block index
    for (int kt = 0; kt < NK; ++kt) {
        if (kt + 1 < NK) stage(cur ^ 1, (kt + 1) << 5);   // prefetch flies under compute
        short8 af[4], bfr[4];
#pragma unroll
        for (int i = 0; i < 4; ++i) af[i]  = *(const short8*)&As[cur][(wr * 64 + i * 16 + lr) * 32 + rblk * 8];
#pragma unroll
        for (int j = 0; j < 4; ++j) bfr[j] = *(const short8*)&Bs[cur][(wc * 64 + j * 16 + lr) * 32 + rblk * 8];
#pragma unroll
        for (int i = 0; i < 4; ++i)
#pragma unroll
            for (int j = 0; j < 4; ++j)
                acc[i][j] = __builtin_amdgcn_mfma_f32_16x16x32_bf16(af[i], bfr[j], acc[i][j], 0, 0, 0);
        __syncthreads();                              // next buffer complete for everyone
        cur ^= 1;
    }
#pragma unroll
    for (int i = 0; i < 4; ++i)
#pragma unroll
        for (int j = 0; j < 4; ++j)
#pragma unroll
            for (int r = 0; r < 4; ++r) {
                int gm = bm0 + wr * 64 + i * 16 + lg * 4 + r;
                int gn = bn0 + wc * 64 + j * 16 + lr;
                if (gm < M) {
                    float c = acc[i][j][r] + bias[gn];
                    if (MODE == 0) {
                        if (gn < 768) c *= 0.125f;    // fold 1/sqrt(Dh) into Q
                        ((unsigned short*)out)[(size_t)gm * N + gn] = f2bf(c);
                    } else if (MODE == 1) {
                        ((float*)out)[(size_t)gm * N + gn] = c + resid[(size_t)gm * N + gn];
                    } else {
                        float g = 0.5f * c * (1.f + erff(c * 0.70710678118f));
                        ((unsigned short*)out)[(size_t)gm * N + gn] = f2bf(g);
                    }
                }
            }
}

// ---------------- MFMA attention: one block per (b,h), 4 waves ----------------
__global__ __launch_bounds__(256)
void attn_mfma(const unsigned short* __restrict__ qkv, const int* __restrict__ mask,
               unsigned short* __restrict__ ctx) {
    __shared__ unsigned short Ks[208 * 64];
    __shared__ unsigned short Vt[64 * 256];
    __shared__ unsigned short Psl[4][16 * 40];
    __shared__ float maskadj[224];
    const int bh = blockIdx.x, b = bh / 12, h = bh - b * 12;
    const int tid = threadIdx.x, l = tid & 63, w = tid >> 6;
    const int lr = l & 15, lg = l >> 4;
    const unsigned short* Qg = qkv + (size_t)b * 197 * 2304 + h * 64;
    const unsigned short* Kg = Qg + 768;
    const unsigned short* Vg = Qg + 1536;

    if (tid < 224)
        maskadj[tid] = tid < 197 ? -10000.f * (1.f - (float)mask[b * 197 + tid]) : -1e30f;

    for (int c = w; c < 26; c += 4) {
        int row = c * 8 + (l >> 3);
        int rc = row < 197 ? row : 196;
        int blk = (l & 7) ^ (row & 7);
        g2l16(Kg + (size_t)rc * 2304 + blk * 8, &Ks[c * 8 * 64]);
    }
    {
        int jj = tid >> 3, db = tid & 7;
#pragma unroll
        for (int it = 0; it < 7; ++it) {
            int j = it * 32 + jj;
            short8 v = (short8){0, 0, 0, 0, 0, 0, 0, 0};
            if (j < 197) v = *(const short8*)(Vg + (size_t)j * 2304 + db * 8);
#pragma unroll
            for (int e = 0; e < 8; ++e) {
                int d = db * 8 + e;
                Vt[d * 256 + (((j >> 3) ^ (d & 7)) * 8) + (j & 7)] = (unsigned short)v[e];
            }
        }
    }
    __syncthreads();

    for (int t = w; t < 13; t += 4) {
        const int q0 = t * 16;
        int qr = q0 + lr; qr = qr < 197 ? qr : 196;
        const short8 qf0 = *(const short8*)(Qg + (size_t)qr * 2304 + lg * 8);
        const short8 qf1 = *(const short8*)(Qg + (size_t)qr * 2304 + 32 + lg * 8);

        f32x4 sc[13];
#pragma unroll
        for (int kt = 0; kt < 13; ++kt) {
            const int krow = kt * 16 + lr;
            const short8 kf0 = *(const short8*)&Ks[krow * 64 + ((lg ^ (lr & 7)) * 8)];
            const short8 kf1 = *(const short8*)&Ks[krow * 64 + (((4 + lg) ^ (lr & 7)) * 8)];
            f32x4 a = (f32x4){0.f, 0.f, 0.f, 0.f};
            a = __builtin_amdgcn_mfma_f32_16x16x32_bf16(qf0, kf0, a, 0, 0, 0);
            a = __builtin_amdgcn_mfma_f32_16x16x32_bf16(qf1, kf1, a, 0, 0, 0);
            sc[kt] = a;
        }
        float mx[4] = {-1e30f, -1e30f, -1e30f, -1e30f};
#pragma unroll
        for (int kt = 0; kt < 13; ++kt) {
            float ma = maskadj[kt * 16 + lr];
#pragma unroll
            for (int r = 0; r < 4; ++r) {
                sc[kt][r] += ma;
                mx[r] = fmaxf(mx[r], sc[kt][r]);
            }
        }
#pragma unroll
        for (int r = 0; r < 4; ++r) {
            mx[r] = fmaxf(mx[r], __shfl_xor(mx[r], 1));
            mx[r] = fmaxf(mx[r], __shfl_xor(mx[r], 2));
            mx[r] = fmaxf(mx[r], __shfl_xor(mx[r], 4));
            mx[r] = fmaxf(mx[r], __shfl_xor(mx[r], 8));
        }
        float sm[4] = {0.f, 0.f, 0.f, 0.f};
#pragma unroll
        for (int kt = 0; kt < 13; ++kt)
#pragma unroll
            for (int r = 0; r < 4; ++r) {
                float p = __expf(sc[kt][r] - mx[r]);
                sc[kt][r] = p;
                sm[r] += p;
            }
#pragma unroll
        for (int r = 0; r < 4; ++r) {
            sm[r] += __shfl_xor(sm[r], 1);
            sm[r] += __shfl_xor(sm[r], 2);
            sm[r] += __shfl_xor(sm[r], 4);
            sm[r] += __shfl_xor(sm[r], 8);
            sm[r] = 1.f / sm[r];
        }
        f32x4 ao[4];
#pragma unroll
        for (int dt = 0; dt < 4; ++dt) ao[dt] = (f32x4){0.f, 0.f, 0.f, 0.f};
        unsigned short* Pw = &Psl[w][0];
#pragma unroll
        for (int ks = 0; ks < 7; ++ks) {
#pragma unroll
            for (int tl = 0; tl < 2; ++tl) {
                const int kt = ks * 2 + tl;
#pragma unroll
                for (int r = 0; r < 4; ++r) {
                    unsigned short pv = 0;
                    if (kt < 13) pv = f2bf(sc[kt][r] * sm[r]);
                    Pw[(lg * 4 + r) * 40 + tl * 16 + lr] = pv;
                }
            }
            const short8 pf = *(const short8*)&Pw[lr * 40 + lg * 8];
#pragma unroll
            for (int dt = 0; dt < 4; ++dt) {
                const int drow = dt * 16 + lr;
                const short8 vf = *(const short8*)&Vt[drow * 256 + (((4 * ks + lg) ^ (lr & 7)) * 8)];
                ao[dt] = __builtin_amdgcn_mfma_f32_16x16x32_bf16(vf, pf, ao[dt], 0, 0, 0);
            }
        }
        const int q = q0 + lr;
        if (q < 197) {
            unsigned short* crow = ctx + ((size_t)b * 197 + q) * 768 + h * 64;
#pragma unroll
            for (int dt = 0; dt < 4; ++dt) {
                union { unsigned short u[4]; uint2 v; } pk;
#pragma unroll
                for (int r = 0; r < 4; ++r) pk.u[r] = f2bf(ao[dt][r]);
                *(uint2*)(crow + dt * 16 + lg * 4) = pk.v;
            }
        }
    }
}

extern "C" void kernel_launch(void* const* d_in, const int* in_sizes, int n_in,
                              void* d_out, int out_size, void* d_ws, size_t ws_size,
                              hipStream_t stream) {
    const float* x    = (const float*)d_in[0];
    const float* Wq   = (const float*)d_in[1];
    const float* bq   = (const float*)d_in[2];
    const float* Wk   = (const float*)d_in[3];
    const float* bk   = (const float*)d_in[4];
    const float* Wv   = (const float*)d_in[5];
    const float* bv   = (const float*)d_in[6];
    const float* Wo   = (const float*)d_in[7];
    const float* bo   = (const float*)d_in[8];
    const float* ln1w = (const float*)d_in[9];
    const float* ln1b = (const float*)d_in[10];
    const float* W1   = (const float*)d_in[11];
    const float* b1   = (const float*)d_in[12];
    const float* W2   = (const float*)d_in[13];
    const float* b2   = (const float*)d_in[14];
    const float* ln2w = (const float*)d_in[15];
    const float* ln2b = (const float*)d_in[16];
    const int*   mask = (const int*)d_in[17];

    size_t off = 0;
    auto nxt = [&](size_t bytes) -> void* {
        void* r = (char*)d_ws + off; off += (bytes + 255) & ~(size_t)255; return r;
    };
    unsigned short* hbuf  = (unsigned short*)nxt((size_t)BS_ * 768 * 2);
    unsigned short* qkvg  = (unsigned short*)nxt((size_t)BS_ * 3072 * 2);  // QKV (2304 cols), reused as FFN1 out (3072)
    unsigned short* wqkvT = (unsigned short*)nxt((size_t)2304 * 768 * 2);
    unsigned short* woT   = (unsigned short*)nxt((size_t)768 * 768 * 2);
    unsigned short* w1T   = (unsigned short*)nxt((size_t)3072 * 768 * 2);
    unsigned short* w2T   = (unsigned short*)nxt((size_t)768 * 3072 * 2);
    float*          bcat  = (float*)nxt(2304 * 4);
    unsigned short* ctx   = (unsigned short*)nxt((size_t)BS_ * 768 * 2);
    (void)ws_size; (void)in_sizes; (void)n_in; (void)out_size;

    transpose_all<<<6913, dim3(32, 8), 0, stream>>>(Wq, Wk, Wv, Wo, W1, W2, bq, bk, bv,
                                                    wqkvT, woT, w1T, w2T, bcat);
    ln_kernel<<<BS_, 256, 0, stream>>>(x, ln1w, ln1b, hbuf);
    gemm_bf16<0><<<dim3(18, 99), 256, 0, stream>>>(hbuf, wqkvT, bcat, nullptr, qkvg, BS_, 2304, 768);
    attn_mfma<<<768, 256, 0, stream>>>(qkvg, mask, ctx);
    gemm_bf16<1><<<dim3(6, 99), 256, 0, stream>>>(ctx, woT, bo, x, d_out, BS_, 768, 768);
    ln_kernel<<<BS_, 256, 0, stream>>>((const float*)d_out, ln2w, ln2b, hbuf);
    gemm_bf16<2><<<dim3(24, 99), 256, 0, stream>>>(hbuf, w1T, b1, nullptr, qkvg, BS_, 3072, 768);
    gemm_bf16<1><<<dim3(6, 99), 256, 0, stream>>>(qkvg, w2T, b2, (const float*)d_out, d_out, BS_, 768, 3072);
}